// Round 8
// baseline (610.109 us; speedup 1.0000x reference)
//
#include <hip/hip_runtime.h>
#include <stdint.h>

// MPS classifier forward, MI355X.
//   k1  : (127,2) blocks, 2 round-1 basis products per block (A-row split)
//   k1b : (16,63) blocks, round-2 basis TT_t = T1_p @ T2_q  (batch-independent)
//   k1c : (63,4) blocks, Gram partials over K-chunks
//   k2ns: 127 blocks: bx<63 -> coeffs/norms/logs (sums Gram partials), coeffs
//         pre-scaled by 1/n; bx>=63 -> special chain rounds 1+2
//   k2c : (32,63) combine M0 = sum_t c'_t TT_t; 2 elems/thread, 64 batches per
//         block. RULE: every TT element read by EXACTLY ONE block (no z-split —
//         replication thrashes per-XCD L2: round-7 FETCH 849 MB, 300 us).
//   R3..R6: pairwise rounds (roundk, 1024 thr, 16 waves)
//   r7f : R7 + R8 + logits fused, 64 blocks

typedef unsigned short u16;
typedef __attribute__((ext_vector_type(8))) short short8;
typedef __attribute__((ext_vector_type(4))) float f32x4;

#define HP 136  // LDS row stride in bf16: 272 B, 16B-aligned, 2-way-bank-free

__device__ __forceinline__ u16 f2b(float f) {
  uint32_t u = __builtin_bit_cast(uint32_t, f);
  u += 0x7FFFu + ((u >> 16) & 1u);
  return (u16)(u >> 16);
}
__device__ __forceinline__ float b2f(u16 b) {
  uint32_t u = ((uint32_t)b) << 16;
  return __builtin_bit_cast(float, u);
}

struct AccW { f32x4 t[2][2]; };  // 16-wave config: 32x32 wave tile

// 1024-thread (16-wave) 128x128x128. A: [m][k] LDS, B: [n][k] LDS.
__device__ __forceinline__ void mfma_w16(const u16* Alds, const u16* Blds,
                                         AccW& acc) {
  const int tid = threadIdx.x;
  const int wid = tid >> 6, lane = tid & 63;
  const int wm = (wid >> 2) * 32, wn = (wid & 3) * 32;
  const int l16 = lane & 15, quad = lane >> 4;
#pragma unroll
  for (int tm = 0; tm < 2; tm++)
#pragma unroll
    for (int tn = 0; tn < 2; tn++)
      acc.t[tm][tn] = (f32x4){0.f, 0.f, 0.f, 0.f};
#pragma unroll
  for (int kk = 0; kk < 128; kk += 32) {
    short8 af[2], bf[2];
#pragma unroll
    for (int t = 0; t < 2; t++) {
      af[t] = *(const short8*)(Alds + (wm + t * 16 + l16) * HP + kk + quad * 8);
      bf[t] = *(const short8*)(Blds + (wn + t * 16 + l16) * HP + kk + quad * 8);
    }
#pragma unroll
    for (int tm = 0; tm < 2; tm++)
#pragma unroll
      for (int tn = 0; tn < 2; tn++)
        acc.t[tm][tn] = __builtin_amdgcn_mfma_f32_16x16x32_bf16(
            af[tm], bf[tn], acc.t[tm][tn], 0, 0, 0);
  }
}

__device__ __forceinline__ float acc_sumsq(const AccW& acc) {
  float ss = 0.f;
#pragma unroll
  for (int tm = 0; tm < 2; tm++)
#pragma unroll
    for (int tn = 0; tn < 2; tn++)
#pragma unroll
      for (int i = 0; i < 4; i++) {
        float v = acc.t[tm][tn][i];
        ss += v * v;
      }
  return ss;
}

// Write acc into bounce LDS (stride HP). transposed -> buffer row = col index.
// C/D layout (m89): row = quad*4 + reg, col = lane&15 per 16x16 tile.
__device__ __forceinline__ void bounce_store(u16* Lb, const AccW& acc, float scale,
                                             bool transposed) {
  const int tid = threadIdx.x;
  const int wid = tid >> 6, lane = tid & 63;
  const int wm = (wid >> 2) * 32, wn = (wid & 3) * 32;
  const int l16 = lane & 15, quad = lane >> 4;
#pragma unroll
  for (int tm = 0; tm < 2; tm++)
#pragma unroll
    for (int tn = 0; tn < 2; tn++)
#pragma unroll
      for (int i = 0; i < 4; i++) {
        int r = wm + tm * 16 + quad * 4 + i;
        int c = wn + tn * 16 + l16;
        int key = transposed ? c : r, sec = transposed ? r : c;
        Lb[key * HP + sec] = f2b(acc.t[tm][tn][i] * scale);
      }
}

// 1024 threads: copy bounce LDS -> global, fully coalesced uint4.
__device__ __forceinline__ void copy_out(const u16* Lb, u16* out) {
  const int tid = threadIdx.x;
#pragma unroll
  for (int i = 0; i < 2; i++) {
    int g8 = tid + i * 1024;  // 0..2047 uint4 units
    int row = g8 >> 4, c8 = g8 & 15;
    *(uint4*)(out + g8 * 8) = *(const uint4*)(Lb + row * HP + c8 * 8);
  }
}

__device__ __forceinline__ float block_sum(float v, float* red, int nw) {
#pragma unroll
  for (int off = 32; off > 0; off >>= 1) v += __shfl_down(v, off);
  int wid = threadIdx.x >> 6;
  if ((threadIdx.x & 63) == 0) red[wid] = v;
  __syncthreads();
  if (threadIdx.x == 0) {
    float s = 0.f;
    for (int w = 0; w < nw; w++) s += red[w];
    red[0] = s;
  }
  __syncthreads();
  float s = red[0];
  __syncthreads();
  return s;
}

// ---------------- k1: two round-1 basis products per block (A-row split) -----
__global__ __launch_bounds__(1024) void k1(const float* __restrict__ cores,
                                           u16* __restrict__ T) {
  __shared__ u16 Ald[128 * HP], B0[128 * HP], B1[128 * HP];
  const int j = blockIdx.x;   // 0..126 -> cores (2j+1, 2j+2)
  const int p = blockIdx.y;   // 0: A0 row (coeffs 1,b), 1: A1 row (coeffs a,ab)
  const float* c1 = cores + (size_t)(2 * j + 1) * 32768;
  const float* c2 = cores + (size_t)(2 * j + 2) * 32768;
  const int tid = threadIdx.x;
#pragma unroll 4
  for (int i = 0; i < 16; i++) {
    int lh = tid + i * 1024;
    int l = lh >> 7, h = lh & 127;
    float a0 = c1[(l * 2 + 0) * 128 + h];
    float av = p ? (c1[(l * 2 + 1) * 128 + h] - a0) : a0;
    Ald[l * HP + h] = f2b(av);
    float b0 = c2[(l * 2 + 0) * 128 + h];
    float b1 = c2[(l * 2 + 1) * 128 + h];
    B0[h * HP + l] = f2b(b0);  // B basis transposed in LDS
    B1[h * HP + l] = f2b(b1 - b0);
  }
  __syncthreads();
  const bool tr = (j % 2) == 0;  // even -> consumed as B operand -> store C^T
  u16* Tj = T + ((size_t)j * 4 + p * 2) * 16384;
  AccW q0, q1;
  mfma_w16(Ald, B0, q0);
  mfma_w16(Ald, B1, q1);
  __syncthreads();  // A dead -> bounce
  bounce_store(Ald, q0, 1.f, tr); __syncthreads();
  copy_out(Ald, Tj + 0 * 16384);  __syncthreads();
  bounce_store(Ald, q1, 1.f, tr); __syncthreads();
  copy_out(Ald, Tj + 1 * 16384);
}

// ---------------- k1b: round-2 basis TT_t = T1_p @ T2_q ----------------
__global__ __launch_bounds__(1024, 8) void k1b(const u16* __restrict__ T,
                                               u16* __restrict__ TT) {
  __shared__ u16 Ald[128 * HP], Bld[128 * HP];
  const int t = blockIdx.x;   // 0..15 : p = t>>2, q = t&3
  const int j2 = blockIdx.y;  // 0..62
  const int m1 = 2 * j2 + 1, m2 = 2 * j2 + 2;
  const u16* TA = T + ((size_t)m1 * 4 + (t >> 2)) * 16384;  // odd -> row-major
  const u16* TB = T + ((size_t)m2 * 4 + (t & 3)) * 16384;   // even -> [n][k] flat
  const int tid = threadIdx.x;
#pragma unroll
  for (int i = 0; i < 2; i++) {
    int g8 = tid + i * 1024;
    int r = g8 >> 4, c8 = g8 & 15;
    *(uint4*)(Ald + r * HP + c8 * 8) = *(const uint4*)(TA + g8 * 8);
    *(uint4*)(Bld + r * HP + c8 * 8) = *(const uint4*)(TB + g8 * 8);
  }
  __syncthreads();
  AccW acc;
  mfma_w16(Ald, Bld, acc);
  __syncthreads();
  bounce_store(Ald, acc, 1.f, (j2 % 2) == 0);
  __syncthreads();
  copy_out(Ald, TT + ((size_t)j2 * 16 + t) * 16384);
}

// ---------------- k1c: Gram partials G[j2][kc] = V V^T over K-chunk ----------
__global__ __launch_bounds__(256) void k1c(const u16* __restrict__ TT,
                                           float* __restrict__ Gpart) {
  __shared__ float Gp[1024];
  const int j2 = blockIdx.x, kc = blockIdx.y;
  const int tid = threadIdx.x;
  const int w = tid >> 6, lane = tid & 63;
  const int l16 = lane & 15, quad = lane >> 4;
  const u16* V = TT + (size_t)j2 * 16 * 16384 + (size_t)l16 * 16384;
  const int k0 = kc * 4096 + w * 1024;
  f32x4 acc = (f32x4){0.f, 0.f, 0.f, 0.f};
  for (int kk = k0; kk < k0 + 1024; kk += 32) {
    short8 av = *(const short8*)(V + kk + quad * 8);
    acc = __builtin_amdgcn_mfma_f32_16x16x32_bf16(av, av, acc, 0, 0, 0);
  }
#pragma unroll
  for (int i = 0; i < 4; i++)
    Gp[w * 256 + (quad * 4 + i) * 16 + l16] = acc[i];
  __syncthreads();
  Gpart[((size_t)j2 * 4 + kc) * 256 + tid] =
      Gp[tid] + Gp[256 + tid] + Gp[512 + tid] + Gp[768 + tid];
}

// ---------------- k2ns: coeffs/norms/logs (bx<63) + special chain (bx>=63) ----
__global__ __launch_bounds__(128) void k2ns(const float* __restrict__ x,
                                            const float* __restrict__ Gpart,
                                            const float* __restrict__ core0,
                                            const float* __restrict__ cores,
                                            const u16* __restrict__ T,
                                            float* __restrict__ cbuf,
                                            float* __restrict__ sA,
                                            float* __restrict__ logs) {
  __shared__ float Gs[256];
  __shared__ float svec[128];
  __shared__ float red[8];
  const int bx = blockIdx.x, tid = threadIdx.x;
  if (bx < 63) {
    const int j2 = bx;
#pragma unroll
    for (int i = 0; i < 2; i++) {
      int t2 = tid + i * 128;
      float s = 0.f;
#pragma unroll
      for (int kc = 0; kc < 4; kc++)
        s += Gpart[((size_t)j2 * 4 + kc) * 256 + t2];
      Gs[t2] = s;
    }
    __syncthreads();
    if (tid < 64) {
      const int b = tid;
      const float* xb = x + b * 256;
      const int m1 = 2 * j2 + 1, m2 = 2 * j2 + 2;
      float a1 = xb[2 * m1 + 2], b1 = xb[2 * m1 + 3];
      float a2 = xb[2 * m2 + 2], b2 = xb[2 * m2 + 3];
      float c1[4] = {1.f, b1, a1, a1 * b1};
      float c2[4] = {1.f, b2, a2, a2 * b2};
      float c[16];
#pragma unroll
      for (int p = 0; p < 4; p++)
#pragma unroll
        for (int q = 0; q < 4; q++) c[p * 4 + q] = c1[p] * c2[q];
      float n2 = 0.f;
#pragma unroll
      for (int t = 0; t < 16; t++) {
        float s = 0.f;
#pragma unroll
        for (int u = 0; u < 16; u++) s += Gs[t * 16 + u] * c[u];
        n2 += c[t] * s;
      }
      float n = fmaxf(sqrtf(n2), 1e-12f);
      logs[b * 127 + 1 + j2] = logf(n);
      float inv = 1.f / n;
#pragma unroll
      for (int t = 0; t < 16; t++)
        cbuf[((size_t)j2 * 64 + b) * 16 + t] = c[t] * inv;  // prescaled by 1/n
    }
  } else {
    const int b = bx - 63;
    const float* xb = x + b * 256;
    float x0 = xb[0], x1 = xb[1];
    svec[tid] = core0[tid] * (1.f - x0) + core0[128 + tid] * x0;
    __syncthreads();
    float acc1 = 0.f;
    for (int k = 0; k < 128; k++) {
      float m0 = cores[(k * 2 + 0) * 128 + tid];
      float m1 = cores[(k * 2 + 1) * 128 + tid];
      acc1 += svec[k] * (m0 + x1 * (m1 - m0));
    }
    float tot = block_sum(acc1 * acc1, red, 2);
    float n1 = fmaxf(sqrtf(tot), 1e-12f);
    float ln = logf(n1);
    svec[tid] = acc1 / n1;
    __syncthreads();
    float a = xb[2], bb = xb[3], ab = a * bb;
    float acc2 = 0.f;
    for (int k8 = 0; k8 < 16; k8++) {
      union { uint4 v; u16 s[8]; } q00, q01, q10, q11;
      q00.v = *(const uint4*)(T + tid * 128 + k8 * 8);
      q01.v = *(const uint4*)(T + 16384 + tid * 128 + k8 * 8);
      q10.v = *(const uint4*)(T + 32768 + tid * 128 + k8 * 8);
      q11.v = *(const uint4*)(T + 49152 + tid * 128 + k8 * 8);
#pragma unroll
      for (int e = 0; e < 8; e++) {
        float pk = b2f(q00.s[e]) + a * b2f(q10.s[e]) + bb * b2f(q01.s[e]) +
                   ab * b2f(q11.s[e]);
        acc2 += svec[k8 * 8 + e] * pk;
      }
    }
    float tot2 = block_sum(acc2 * acc2, red, 2);
    float n2 = fmaxf(sqrtf(tot2), 1e-12f);
    sA[b * 128 + tid] = acc2 / n2;
    if (tid == 0) logs[b * 127 + 0] = ln + logf(n2);
  }
}

// ---------------- k2c: combine, single TT fetch, 2 elems/thread --------------
// grid (32,63): each TT element read by exactly one block (no replication).
__global__ __launch_bounds__(256, 8) void k2c(const u16* __restrict__ TT,
                                              const float* __restrict__ cbuf,
                                              u16* __restrict__ M0) {
  __shared__ float cbS[1024];  // [b][t] prescaled
  const int slice = blockIdx.x;  // 0..31, 512 elems each
  const int j2 = blockIdx.y;
  const int tid = threadIdx.x;
  for (int i = tid; i < 1024; i += 256) cbS[i] = cbuf[(size_t)j2 * 1024 + i];
  const int e0 = slice * 512 + tid * 2;
  float v[16][2];
#pragma unroll
  for (int t = 0; t < 16; t++) {
    union { uint32_t u; u16 s[2]; } q;
    q.u = *(const uint32_t*)(TT + ((size_t)j2 * 16 + t) * 16384 + e0);
    v[t][0] = b2f(q.s[0]);
    v[t][1] = b2f(q.s[1]);
  }
  __syncthreads();
  u16* out = M0 + (size_t)j2 * 16384 + e0;
#pragma unroll 4
  for (int b = 0; b < 64; b++) {
    const float* cb = cbS + b * 16;
    float o0 = 0.f, o1 = 0.f;
#pragma unroll
    for (int t = 0; t < 16; t++) {
      float ct = cb[t];
      o0 += ct * v[t][0];
      o1 += ct * v[t][1];
    }
    union { uint32_t u; u16 s[2]; } r;
    r.s[0] = f2b(o0);
    r.s[1] = f2b(o1);
    *(uint32_t*)(out + (size_t)b * 63 * 16384) = r.u;
  }
}

// ---------------- R3..R6: pairwise round (1024 threads) ----------------
__global__ __launch_bounds__(1024, 8) void roundk(const u16* __restrict__ In,
                                                  u16* __restrict__ Out,
                                                  const float* __restrict__ sIn,
                                                  float* __restrict__ sOut,
                                                  float* __restrict__ logs,
                                                  int count_in, int slot0) {
  __shared__ u16 Ald[128 * HP], Bld[128 * HP];
  __shared__ float red[16];
  const int b = blockIdx.y, p = blockIdx.x, tid = threadIdx.x;

  if (p == 0) {
    float* svec = (float*)Ald;
    if (tid < 128) svec[tid] = sIn[b * 128 + tid];
    __syncthreads();
    const u16* M = In + (size_t)b * count_in * 16384;  // In[b][0], transposed
    float acc = 0.f;
    if (tid < 128) {
      for (int k8 = 0; k8 < 16; k8++) {
        union { uint4 v; u16 s[8]; } q;
        q.v = *(const uint4*)(M + tid * 128 + k8 * 8);
#pragma unroll
        for (int e = 0; e < 8; e++) acc += svec[k8 * 8 + e] * b2f(q.s[e]);
      }
    }
    float tot = block_sum((tid < 128) ? acc * acc : 0.f, red, 16);
    float n = fmaxf(sqrtf(tot), 1e-12f);
    if (tid < 128) sOut[b * 128 + tid] = acc / n;
    if (tid == 0) logs[b * 127 + slot0] = logf(n);
  } else {
    const u16* A = In + ((size_t)b * count_in + (2 * p - 1)) * 16384;
    const u16* Bm = In + ((size_t)b * count_in + (2 * p)) * 16384;
#pragma unroll
    for (int i = 0; i < 2; i++) {
      int g8 = tid + i * 1024;
      int r = g8 >> 4, c8 = g8 & 15;
      *(uint4*)(Ald + r * HP + c8 * 8) = *(const uint4*)(A + g8 * 8);
      *(uint4*)(Bld + r * HP + c8 * 8) = *(const uint4*)(Bm + g8 * 8);
    }
    __syncthreads();
    AccW acc;
    mfma_w16(Ald, Bld, acc);
    float tot = block_sum(acc_sumsq(acc), red, 16);
    float n = fmaxf(sqrtf(tot), 1e-12f);
    if (tid == 0) logs[b * 127 + slot0 + p] = logf(n);
    int m = p - 1;
    int count_out = (count_in - 1) / 2;
    bounce_store(Ald, acc, 1.f / n, (m % 2) == 0);  // block_sum ended w/ barrier
    __syncthreads();
    copy_out(Ald, Out + ((size_t)b * count_out + m) * 16384);
  }
}

// ---------------- r7f: R7 + R8 + logits, one block per batch ----------------
__global__ __launch_bounds__(1024, 8) void r7f(const u16* __restrict__ In,
                                               const float* __restrict__ sIn,
                                               const float* __restrict__ logs,
                                               const float* __restrict__ cls,
                                               float* __restrict__ out) {
  __shared__ u16 Ald[128 * HP], Bld[128 * HP];
  __shared__ float svec[128], ovec[128], red[16];
  const int b = blockIdx.x, tid = threadIdx.x;
  if (tid < 128) svec[tid] = sIn[b * 128 + tid];
  const u16* A = In + ((size_t)b * 3 + 1) * 16384;   // row-major
  const u16* Bm = In + ((size_t)b * 3 + 2) * 16384;  // transposed
#pragma unroll
  for (int i = 0; i < 2; i++) {
    int g8 = tid + i * 1024;
    int r = g8 >> 4, c8 = g8 & 15;
    *(uint4*)(Ald + r * HP + c8 * 8) = *(const uint4*)(A + g8 * 8);
    *(uint4*)(Bld + r * HP + c8 * 8) = *(const uint4*)(Bm + g8 * 8);
  }
  __syncthreads();
  AccW acc;
  mfma_w16(Ald, Bld, acc);
  float tot = block_sum(acc_sumsq(acc), red, 16);
  float n1 = fmaxf(sqrtf(tot), 1e-12f);
  float lg = logf(n1);
  // C (normalized) -> bounce LDS transposed: Lb[c*HP + r]
  bounce_store(Ald, acc, 1.f / n1, true);
  // special dot with In[b*3+0] (global, transposed layout)
  const u16* M0p = In + (size_t)b * 3 * 16384;
  float acc0 = 0.f;
  if (tid < 128) {
    for (int k8 = 0; k8 < 16; k8++) {
      union { uint4 v; u16 s[8]; } q;
      q.v = *(const uint4*)(M0p + tid * 128 + k8 * 8);
#pragma unroll
      for (int e = 0; e < 8; e++) acc0 += svec[k8 * 8 + e] * b2f(q.s[e]);
    }
  }
  float tot0 = block_sum((tid < 128) ? acc0 * acc0 : 0.f, red, 16);
  float n0 = fmaxf(sqrtf(tot0), 1e-12f);
  lg += logf(n0);
  if (tid < 128) ovec[tid] = acc0 / n0;
  __syncthreads();
  // R8: res[c] = sum_r ovec[r] * C[r][c]  (C in Ald as [c][r])
  float acc2 = 0.f;
  if (tid < 128) {
    for (int r = 0; r < 128; r++) acc2 += ovec[r] * b2f(Ald[tid * HP + r]);
  }
  float tot2 = block_sum((tid < 128) ? acc2 * acc2 : 0.f, red, 16);
  float n2 = fmaxf(sqrtf(tot2), 1e-12f);
  lg += logf(n2);
  if (tid < 128) svec[tid] = acc2 / n2;
  __syncthreads();
  if (tid < 10) {
    float a = 0.f;
    for (int h = 0; h < 128; h++) a += svec[h] * cls[tid * 128 + h];
    float L = lg;
    for (int i = 0; i < 124; i++) L += logs[b * 127 + i];
    out[b * 10 + tid] = a + L;
  }
}

extern "C" void kernel_launch(void* const* d_in, const int* in_sizes, int n_in,
                              void* d_out, int out_size, void* d_ws, size_t ws_size,
                              hipStream_t stream) {
  (void)in_sizes; (void)n_in; (void)out_size; (void)ws_size;
  const float* x     = (const float*)d_in[0];  // (64,256)
  const float* core0 = (const float*)d_in[1];  // (1,2,128)
  const float* cores = (const float*)d_in[2];  // (255,128,2,128)
  const float* cls   = (const float*)d_in[3];  // (10,128)
  float* out = (float*)d_out;
  char* ws = (char*)d_ws;

  // Region A (65 MB): early = T (16.6 MB) + TT (33 MB); later reused as M1.
  constexpr size_t SZ_T  = (size_t)127 * 4 * 16384 * 2;   //  16,646,144
  constexpr size_t SZ_A  = (size_t)64 * 31 * 16384 * 2;   //  65,011,712 (M1)
  constexpr size_t SZ_M0 = (size_t)64 * 63 * 16384 * 2;   // 132,120,576

  u16*   T    = (u16*)(ws);
  u16*   TT   = (u16*)(ws + SZ_T);
  u16*   M1   = (u16*)(ws);            // aliases T+TT after k2c completes
  u16*   M0   = (u16*)(ws + SZ_A);
  char*  tail0 = ws + SZ_A + SZ_M0;
  float* Gpart = (float*)(tail0);                      // 63*4*256*4 = 258,048
  float* cbuf = (float*)(tail0 + 262144);              // 63*64*16*4 = 258,048
  float* sA   = (float*)(tail0 + 262144 + 262144);
  float* sB   = (float*)(tail0 + 262144 + 262144 + 32768);
  float* logs = (float*)(tail0 + 262144 + 262144 + 65536);

  k1  <<<dim3(127, 2), 1024, 0, stream>>>(cores, T);
  k1b <<<dim3(16, 63), 1024, 0, stream>>>(T, TT);
  k1c <<<dim3(63, 4), 256, 0, stream>>>(TT, Gpart);
  k2ns<<<dim3(127), 128, 0, stream>>>(x, Gpart, core0, cores, T, cbuf, sA, logs);
  k2c <<<dim3(32, 63), 256, 0, stream>>>(TT, cbuf, M0);
  // log slots: 0 special(r1+r2), 1..63 pairs(r1+r2), R3 64..95, R4 96..111,
  //            R5 112..119, R6 120..123; r7f computes 124..126 locally.
  roundk<<<dim3(32, 64), 1024, 0, stream>>>(M0, M1, sA, sB, logs, 63, 64);
  roundk<<<dim3(16, 64), 1024, 0, stream>>>(M1, M0, sB, sA, logs, 31, 96);
  roundk<<<dim3(8, 64),  1024, 0, stream>>>(M0, M1, sA, sB, logs, 15, 112);
  roundk<<<dim3(4, 64),  1024, 0, stream>>>(M1, M0, sB, sA, logs, 7, 120);
  r7f  <<<dim3(64), 1024, 0, stream>>>(M0, sA, logs, cls, out);
}

// Round 9
// 265.905 us; speedup vs baseline: 2.2945x; 2.2945x over previous
//
#include <hip/hip_runtime.h>
#include <stdint.h>

// MPS classifier forward, MI355X.
//   k1  : (127,2) blocks, 2 round-1 basis products per block (A-row split)
//   k1b : (16,63) blocks, round-2 basis TT_t = T1_p @ T2_q  (batch-independent)
//   k1c : (63,4) blocks, Gram partials over K-chunks
//   k2ns: 127 blocks: bx<63 -> coeffs/norms/logs (sums Gram partials), coeffs
//         pre-scaled by 1/n; bx>=63 -> special chain rounds 1+2
//   k2c : (32,63) combine M0 = sum_t c'_t TT_t; 2 elems/thread, 64 batches/block.
//         RULES learned: (1) every TT element read by EXACTLY ONE block (r7:
//         z-replication + spill -> 849 MB fetch); (2) launch_bounds min-waves
//         caps VGPRs (512/minw) — (256,8) capped at 64 VGPR and SPILLED the
//         v[16][*] slice to scratch (r8: FETCH 1.11 GB, VGPR=32). Use (256,4).
//   R3..R6: pairwise rounds (roundk, 1024 thr, 16 waves)
//   r7f : R7 + R8 + logits fused, 64 blocks

typedef unsigned short u16;
typedef __attribute__((ext_vector_type(8))) short short8;
typedef __attribute__((ext_vector_type(4))) float f32x4;

#define HP 136  // LDS row stride in bf16: 272 B, 16B-aligned, 2-way-bank-free

__device__ __forceinline__ u16 f2b(float f) {
  uint32_t u = __builtin_bit_cast(uint32_t, f);
  u += 0x7FFFu + ((u >> 16) & 1u);
  return (u16)(u >> 16);
}
__device__ __forceinline__ float b2f(u16 b) {
  uint32_t u = ((uint32_t)b) << 16;
  return __builtin_bit_cast(float, u);
}

struct AccW { f32x4 t[2][2]; };  // 16-wave config: 32x32 wave tile

// 1024-thread (16-wave) 128x128x128. A: [m][k] LDS, B: [n][k] LDS.
__device__ __forceinline__ void mfma_w16(const u16* Alds, const u16* Blds,
                                         AccW& acc) {
  const int tid = threadIdx.x;
  const int wid = tid >> 6, lane = tid & 63;
  const int wm = (wid >> 2) * 32, wn = (wid & 3) * 32;
  const int l16 = lane & 15, quad = lane >> 4;
#pragma unroll
  for (int tm = 0; tm < 2; tm++)
#pragma unroll
    for (int tn = 0; tn < 2; tn++)
      acc.t[tm][tn] = (f32x4){0.f, 0.f, 0.f, 0.f};
#pragma unroll
  for (int kk = 0; kk < 128; kk += 32) {
    short8 af[2], bf[2];
#pragma unroll
    for (int t = 0; t < 2; t++) {
      af[t] = *(const short8*)(Alds + (wm + t * 16 + l16) * HP + kk + quad * 8);
      bf[t] = *(const short8*)(Blds + (wn + t * 16 + l16) * HP + kk + quad * 8);
    }
#pragma unroll
    for (int tm = 0; tm < 2; tm++)
#pragma unroll
      for (int tn = 0; tn < 2; tn++)
        acc.t[tm][tn] = __builtin_amdgcn_mfma_f32_16x16x32_bf16(
            af[tm], bf[tn], acc.t[tm][tn], 0, 0, 0);
  }
}

__device__ __forceinline__ float acc_sumsq(const AccW& acc) {
  float ss = 0.f;
#pragma unroll
  for (int tm = 0; tm < 2; tm++)
#pragma unroll
    for (int tn = 0; tn < 2; tn++)
#pragma unroll
      for (int i = 0; i < 4; i++) {
        float v = acc.t[tm][tn][i];
        ss += v * v;
      }
  return ss;
}

// Write acc into bounce LDS (stride HP). transposed -> buffer row = col index.
// C/D layout (m89): row = quad*4 + reg, col = lane&15 per 16x16 tile.
__device__ __forceinline__ void bounce_store(u16* Lb, const AccW& acc, float scale,
                                             bool transposed) {
  const int tid = threadIdx.x;
  const int wid = tid >> 6, lane = tid & 63;
  const int wm = (wid >> 2) * 32, wn = (wid & 3) * 32;
  const int l16 = lane & 15, quad = lane >> 4;
#pragma unroll
  for (int tm = 0; tm < 2; tm++)
#pragma unroll
    for (int tn = 0; tn < 2; tn++)
#pragma unroll
      for (int i = 0; i < 4; i++) {
        int r = wm + tm * 16 + quad * 4 + i;
        int c = wn + tn * 16 + l16;
        int key = transposed ? c : r, sec = transposed ? r : c;
        Lb[key * HP + sec] = f2b(acc.t[tm][tn][i] * scale);
      }
}

// 1024 threads: copy bounce LDS -> global, fully coalesced uint4.
__device__ __forceinline__ void copy_out(const u16* Lb, u16* out) {
  const int tid = threadIdx.x;
#pragma unroll
  for (int i = 0; i < 2; i++) {
    int g8 = tid + i * 1024;  // 0..2047 uint4 units
    int row = g8 >> 4, c8 = g8 & 15;
    *(uint4*)(out + g8 * 8) = *(const uint4*)(Lb + row * HP + c8 * 8);
  }
}

__device__ __forceinline__ float block_sum(float v, float* red, int nw) {
#pragma unroll
  for (int off = 32; off > 0; off >>= 1) v += __shfl_down(v, off);
  int wid = threadIdx.x >> 6;
  if ((threadIdx.x & 63) == 0) red[wid] = v;
  __syncthreads();
  if (threadIdx.x == 0) {
    float s = 0.f;
    for (int w = 0; w < nw; w++) s += red[w];
    red[0] = s;
  }
  __syncthreads();
  float s = red[0];
  __syncthreads();
  return s;
}

// ---------------- k1: two round-1 basis products per block (A-row split) -----
__global__ __launch_bounds__(1024) void k1(const float* __restrict__ cores,
                                           u16* __restrict__ T) {
  __shared__ u16 Ald[128 * HP], B0[128 * HP], B1[128 * HP];
  const int j = blockIdx.x;   // 0..126 -> cores (2j+1, 2j+2)
  const int p = blockIdx.y;   // 0: A0 row (coeffs 1,b), 1: A1 row (coeffs a,ab)
  const float* c1 = cores + (size_t)(2 * j + 1) * 32768;
  const float* c2 = cores + (size_t)(2 * j + 2) * 32768;
  const int tid = threadIdx.x;
#pragma unroll 4
  for (int i = 0; i < 16; i++) {
    int lh = tid + i * 1024;
    int l = lh >> 7, h = lh & 127;
    float a0 = c1[(l * 2 + 0) * 128 + h];
    float av = p ? (c1[(l * 2 + 1) * 128 + h] - a0) : a0;
    Ald[l * HP + h] = f2b(av);
    float b0 = c2[(l * 2 + 0) * 128 + h];
    float b1 = c2[(l * 2 + 1) * 128 + h];
    B0[h * HP + l] = f2b(b0);  // B basis transposed in LDS
    B1[h * HP + l] = f2b(b1 - b0);
  }
  __syncthreads();
  const bool tr = (j % 2) == 0;  // even -> consumed as B operand -> store C^T
  u16* Tj = T + ((size_t)j * 4 + p * 2) * 16384;
  AccW q0, q1;
  mfma_w16(Ald, B0, q0);
  mfma_w16(Ald, B1, q1);
  __syncthreads();  // A dead -> bounce
  bounce_store(Ald, q0, 1.f, tr); __syncthreads();
  copy_out(Ald, Tj + 0 * 16384);  __syncthreads();
  bounce_store(Ald, q1, 1.f, tr); __syncthreads();
  copy_out(Ald, Tj + 1 * 16384);
}

// ---------------- k1b: round-2 basis TT_t = T1_p @ T2_q ----------------
__global__ __launch_bounds__(1024, 8) void k1b(const u16* __restrict__ T,
                                               u16* __restrict__ TT) {
  __shared__ u16 Ald[128 * HP], Bld[128 * HP];
  const int t = blockIdx.x;   // 0..15 : p = t>>2, q = t&3
  const int j2 = blockIdx.y;  // 0..62
  const int m1 = 2 * j2 + 1, m2 = 2 * j2 + 2;
  const u16* TA = T + ((size_t)m1 * 4 + (t >> 2)) * 16384;  // odd -> row-major
  const u16* TB = T + ((size_t)m2 * 4 + (t & 3)) * 16384;   // even -> [n][k] flat
  const int tid = threadIdx.x;
#pragma unroll
  for (int i = 0; i < 2; i++) {
    int g8 = tid + i * 1024;
    int r = g8 >> 4, c8 = g8 & 15;
    *(uint4*)(Ald + r * HP + c8 * 8) = *(const uint4*)(TA + g8 * 8);
    *(uint4*)(Bld + r * HP + c8 * 8) = *(const uint4*)(TB + g8 * 8);
  }
  __syncthreads();
  AccW acc;
  mfma_w16(Ald, Bld, acc);
  __syncthreads();
  bounce_store(Ald, acc, 1.f, (j2 % 2) == 0);
  __syncthreads();
  copy_out(Ald, TT + ((size_t)j2 * 16 + t) * 16384);
}

// ---------------- k1c: Gram partials G[j2][kc] = V V^T over K-chunk ----------
__global__ __launch_bounds__(256) void k1c(const u16* __restrict__ TT,
                                           float* __restrict__ Gpart) {
  __shared__ float Gp[1024];
  const int j2 = blockIdx.x, kc = blockIdx.y;
  const int tid = threadIdx.x;
  const int w = tid >> 6, lane = tid & 63;
  const int l16 = lane & 15, quad = lane >> 4;
  const u16* V = TT + (size_t)j2 * 16 * 16384 + (size_t)l16 * 16384;
  const int k0 = kc * 4096 + w * 1024;
  f32x4 acc = (f32x4){0.f, 0.f, 0.f, 0.f};
  for (int kk = k0; kk < k0 + 1024; kk += 32) {
    short8 av = *(const short8*)(V + kk + quad * 8);
    acc = __builtin_amdgcn_mfma_f32_16x16x32_bf16(av, av, acc, 0, 0, 0);
  }
#pragma unroll
  for (int i = 0; i < 4; i++)
    Gp[w * 256 + (quad * 4 + i) * 16 + l16] = acc[i];
  __syncthreads();
  Gpart[((size_t)j2 * 4 + kc) * 256 + tid] =
      Gp[tid] + Gp[256 + tid] + Gp[512 + tid] + Gp[768 + tid];
}

// ---------------- k2ns: coeffs/norms/logs (bx<63) + special chain (bx>=63) ----
__global__ __launch_bounds__(128) void k2ns(const float* __restrict__ x,
                                            const float* __restrict__ Gpart,
                                            const float* __restrict__ core0,
                                            const float* __restrict__ cores,
                                            const u16* __restrict__ T,
                                            float* __restrict__ cbuf,
                                            float* __restrict__ sA,
                                            float* __restrict__ logs) {
  __shared__ float Gs[256];
  __shared__ float svec[128];
  __shared__ float red[8];
  const int bx = blockIdx.x, tid = threadIdx.x;
  if (bx < 63) {
    const int j2 = bx;
#pragma unroll
    for (int i = 0; i < 2; i++) {
      int t2 = tid + i * 128;
      float s = 0.f;
#pragma unroll
      for (int kc = 0; kc < 4; kc++)
        s += Gpart[((size_t)j2 * 4 + kc) * 256 + t2];
      Gs[t2] = s;
    }
    __syncthreads();
    if (tid < 64) {
      const int b = tid;
      const float* xb = x + b * 256;
      const int m1 = 2 * j2 + 1, m2 = 2 * j2 + 2;
      float a1 = xb[2 * m1 + 2], b1 = xb[2 * m1 + 3];
      float a2 = xb[2 * m2 + 2], b2 = xb[2 * m2 + 3];
      float c1[4] = {1.f, b1, a1, a1 * b1};
      float c2[4] = {1.f, b2, a2, a2 * b2};
      float c[16];
#pragma unroll
      for (int p = 0; p < 4; p++)
#pragma unroll
        for (int q = 0; q < 4; q++) c[p * 4 + q] = c1[p] * c2[q];
      float n2 = 0.f;
#pragma unroll
      for (int t = 0; t < 16; t++) {
        float s = 0.f;
#pragma unroll
        for (int u = 0; u < 16; u++) s += Gs[t * 16 + u] * c[u];
        n2 += c[t] * s;
      }
      float n = fmaxf(sqrtf(n2), 1e-12f);
      logs[b * 127 + 1 + j2] = logf(n);
      float inv = 1.f / n;
#pragma unroll
      for (int t = 0; t < 16; t++)
        cbuf[((size_t)j2 * 64 + b) * 16 + t] = c[t] * inv;  // prescaled by 1/n
    }
  } else {
    const int b = bx - 63;
    const float* xb = x + b * 256;
    float x0 = xb[0], x1 = xb[1];
    svec[tid] = core0[tid] * (1.f - x0) + core0[128 + tid] * x0;
    __syncthreads();
    float acc1 = 0.f;
    for (int k = 0; k < 128; k++) {
      float m0 = cores[(k * 2 + 0) * 128 + tid];
      float m1 = cores[(k * 2 + 1) * 128 + tid];
      acc1 += svec[k] * (m0 + x1 * (m1 - m0));
    }
    float tot = block_sum(acc1 * acc1, red, 2);
    float n1 = fmaxf(sqrtf(tot), 1e-12f);
    float ln = logf(n1);
    svec[tid] = acc1 / n1;
    __syncthreads();
    float a = xb[2], bb = xb[3], ab = a * bb;
    float acc2 = 0.f;
    for (int k8 = 0; k8 < 16; k8++) {
      union { uint4 v; u16 s[8]; } q00, q01, q10, q11;
      q00.v = *(const uint4*)(T + tid * 128 + k8 * 8);
      q01.v = *(const uint4*)(T + 16384 + tid * 128 + k8 * 8);
      q10.v = *(const uint4*)(T + 32768 + tid * 128 + k8 * 8);
      q11.v = *(const uint4*)(T + 49152 + tid * 128 + k8 * 8);
#pragma unroll
      for (int e = 0; e < 8; e++) {
        float pk = b2f(q00.s[e]) + a * b2f(q10.s[e]) + bb * b2f(q01.s[e]) +
                   ab * b2f(q11.s[e]);
        acc2 += svec[k8 * 8 + e] * pk;
      }
    }
    float tot2 = block_sum(acc2 * acc2, red, 2);
    float n2 = fmaxf(sqrtf(tot2), 1e-12f);
    sA[b * 128 + tid] = acc2 / n2;
    if (tid == 0) logs[b * 127 + 0] = ln + logf(n2);
  }
}

// ---------------- k2c: combine, single TT fetch, 2 elems/thread --------------
// grid (32,63): each TT element read by exactly one block (no replication).
// launch_bounds (256,4): 128-VGPR cap so v[16][2] stays in registers (no spill).
__global__ __launch_bounds__(256, 4) void k2c(const u16* __restrict__ TT,
                                              const float* __restrict__ cbuf,
                                              u16* __restrict__ M0) {
  __shared__ float cbS[1024];  // [b][t] prescaled
  const int slice = blockIdx.x;  // 0..31, 512 elems each
  const int j2 = blockIdx.y;
  const int tid = threadIdx.x;
  for (int i = tid; i < 1024; i += 256) cbS[i] = cbuf[(size_t)j2 * 1024 + i];
  const int e0 = slice * 512 + tid * 2;
  float v[16][2];
#pragma unroll
  for (int t = 0; t < 16; t++) {
    union { uint32_t u; u16 s[2]; } q;
    q.u = *(const uint32_t*)(TT + ((size_t)j2 * 16 + t) * 16384 + e0);
    v[t][0] = b2f(q.s[0]);
    v[t][1] = b2f(q.s[1]);
  }
  __syncthreads();
  u16* out = M0 + (size_t)j2 * 16384 + e0;
#pragma unroll 4
  for (int b = 0; b < 64; b++) {
    const float* cb = cbS + b * 16;
    float o0 = 0.f, o1 = 0.f;
#pragma unroll
    for (int t = 0; t < 16; t++) {
      float ct = cb[t];
      o0 += ct * v[t][0];
      o1 += ct * v[t][1];
    }
    union { uint32_t u; u16 s[2]; } r;
    r.s[0] = f2b(o0);
    r.s[1] = f2b(o1);
    *(uint32_t*)(out + (size_t)b * 63 * 16384) = r.u;
  }
}

// ---------------- R3..R6: pairwise round (1024 threads) ----------------
__global__ __launch_bounds__(1024, 8) void roundk(const u16* __restrict__ In,
                                                  u16* __restrict__ Out,
                                                  const float* __restrict__ sIn,
                                                  float* __restrict__ sOut,
                                                  float* __restrict__ logs,
                                                  int count_in, int slot0) {
  __shared__ u16 Ald[128 * HP], Bld[128 * HP];
  __shared__ float red[16];
  const int b = blockIdx.y, p = blockIdx.x, tid = threadIdx.x;

  if (p == 0) {
    float* svec = (float*)Ald;
    if (tid < 128) svec[tid] = sIn[b * 128 + tid];
    __syncthreads();
    const u16* M = In + (size_t)b * count_in * 16384;  // In[b][0], transposed
    float acc = 0.f;
    if (tid < 128) {
      for (int k8 = 0; k8 < 16; k8++) {
        union { uint4 v; u16 s[8]; } q;
        q.v = *(const uint4*)(M + tid * 128 + k8 * 8);
#pragma unroll
        for (int e = 0; e < 8; e++) acc += svec[k8 * 8 + e] * b2f(q.s[e]);
      }
    }
    float tot = block_sum((tid < 128) ? acc * acc : 0.f, red, 16);
    float n = fmaxf(sqrtf(tot), 1e-12f);
    if (tid < 128) sOut[b * 128 + tid] = acc / n;
    if (tid == 0) logs[b * 127 + slot0] = logf(n);
  } else {
    const u16* A = In + ((size_t)b * count_in + (2 * p - 1)) * 16384;
    const u16* Bm = In + ((size_t)b * count_in + (2 * p)) * 16384;
#pragma unroll
    for (int i = 0; i < 2; i++) {
      int g8 = tid + i * 1024;
      int r = g8 >> 4, c8 = g8 & 15;
      *(uint4*)(Ald + r * HP + c8 * 8) = *(const uint4*)(A + g8 * 8);
      *(uint4*)(Bld + r * HP + c8 * 8) = *(const uint4*)(Bm + g8 * 8);
    }
    __syncthreads();
    AccW acc;
    mfma_w16(Ald, Bld, acc);
    float tot = block_sum(acc_sumsq(acc), red, 16);
    float n = fmaxf(sqrtf(tot), 1e-12f);
    if (tid == 0) logs[b * 127 + slot0 + p] = logf(n);
    int m = p - 1;
    int count_out = (count_in - 1) / 2;
    bounce_store(Ald, acc, 1.f / n, (m % 2) == 0);  // block_sum ended w/ barrier
    __syncthreads();
    copy_out(Ald, Out + ((size_t)b * count_out + m) * 16384);
  }
}

// ---------------- r7f: R7 + R8 + logits, one block per batch ----------------
__global__ __launch_bounds__(1024, 8) void r7f(const u16* __restrict__ In,
                                               const float* __restrict__ sIn,
                                               const float* __restrict__ logs,
                                               const float* __restrict__ cls,
                                               float* __restrict__ out) {
  __shared__ u16 Ald[128 * HP], Bld[128 * HP];
  __shared__ float svec[128], ovec[128], red[16];
  const int b = blockIdx.x, tid = threadIdx.x;
  if (tid < 128) svec[tid] = sIn[b * 128 + tid];
  const u16* A = In + ((size_t)b * 3 + 1) * 16384;   // row-major
  const u16* Bm = In + ((size_t)b * 3 + 2) * 16384;  // transposed
#pragma unroll
  for (int i = 0; i < 2; i++) {
    int g8 = tid + i * 1024;
    int r = g8 >> 4, c8 = g8 & 15;
    *(uint4*)(Ald + r * HP + c8 * 8) = *(const uint4*)(A + g8 * 8);
    *(uint4*)(Bld + r * HP + c8 * 8) = *(const uint4*)(Bm + g8 * 8);
  }
  __syncthreads();
  AccW acc;
  mfma_w16(Ald, Bld, acc);
  float tot = block_sum(acc_sumsq(acc), red, 16);
  float n1 = fmaxf(sqrtf(tot), 1e-12f);
  float lg = logf(n1);
  // C (normalized) -> bounce LDS transposed: Lb[c*HP + r]
  bounce_store(Ald, acc, 1.f / n1, true);
  // special dot with In[b*3+0] (global, transposed layout)
  const u16* M0p = In + (size_t)b * 3 * 16384;
  float acc0 = 0.f;
  if (tid < 128) {
    for (int k8 = 0; k8 < 16; k8++) {
      union { uint4 v; u16 s[8]; } q;
      q.v = *(const uint4*)(M0p + tid * 128 + k8 * 8);
#pragma unroll
      for (int e = 0; e < 8; e++) acc0 += svec[k8 * 8 + e] * b2f(q.s[e]);
    }
  }
  float tot0 = block_sum((tid < 128) ? acc0 * acc0 : 0.f, red, 16);
  float n0 = fmaxf(sqrtf(tot0), 1e-12f);
  lg += logf(n0);
  if (tid < 128) ovec[tid] = acc0 / n0;
  __syncthreads();
  // R8: res[c] = sum_r ovec[r] * C[r][c]  (C in Ald as [c][r])
  float acc2 = 0.f;
  if (tid < 128) {
    for (int r = 0; r < 128; r++) acc2 += ovec[r] * b2f(Ald[tid * HP + r]);
  }
  float tot2 = block_sum((tid < 128) ? acc2 * acc2 : 0.f, red, 16);
  float n2 = fmaxf(sqrtf(tot2), 1e-12f);
  lg += logf(n2);
  if (tid < 128) svec[tid] = acc2 / n2;
  __syncthreads();
  if (tid < 10) {
    float a = 0.f;
    for (int h = 0; h < 128; h++) a += svec[h] * cls[tid * 128 + h];
    float L = lg;
    for (int i = 0; i < 124; i++) L += logs[b * 127 + i];
    out[b * 10 + tid] = a + L;
  }
}

extern "C" void kernel_launch(void* const* d_in, const int* in_sizes, int n_in,
                              void* d_out, int out_size, void* d_ws, size_t ws_size,
                              hipStream_t stream) {
  (void)in_sizes; (void)n_in; (void)out_size; (void)ws_size;
  const float* x     = (const float*)d_in[0];  // (64,256)
  const float* core0 = (const float*)d_in[1];  // (1,2,128)
  const float* cores = (const float*)d_in[2];  // (255,128,2,128)
  const float* cls   = (const float*)d_in[3];  // (10,128)
  float* out = (float*)d_out;
  char* ws = (char*)d_ws;

  // Region A (65 MB): early = T (16.6 MB) + TT (33 MB); later reused as M1.
  constexpr size_t SZ_T  = (size_t)127 * 4 * 16384 * 2;   //  16,646,144
  constexpr size_t SZ_A  = (size_t)64 * 31 * 16384 * 2;   //  65,011,712 (M1)
  constexpr size_t SZ_M0 = (size_t)64 * 63 * 16384 * 2;   // 132,120,576

  u16*   T    = (u16*)(ws);
  u16*   TT   = (u16*)(ws + SZ_T);
  u16*   M1   = (u16*)(ws);            // aliases T+TT after k2c completes
  u16*   M0   = (u16*)(ws + SZ_A);
  char*  tail0 = ws + SZ_A + SZ_M0;
  float* Gpart = (float*)(tail0);                      // 63*4*256*4 = 258,048
  float* cbuf = (float*)(tail0 + 262144);              // 63*64*16*4 = 258,048
  float* sA   = (float*)(tail0 + 262144 + 262144);
  float* sB   = (float*)(tail0 + 262144 + 262144 + 32768);
  float* logs = (float*)(tail0 + 262144 + 262144 + 65536);

  k1  <<<dim3(127, 2), 1024, 0, stream>>>(cores, T);
  k1b <<<dim3(16, 63), 1024, 0, stream>>>(T, TT);
  k1c <<<dim3(63, 4), 256, 0, stream>>>(TT, Gpart);
  k2ns<<<dim3(127), 128, 0, stream>>>(x, Gpart, core0, cores, T, cbuf, sA, logs);
  k2c <<<dim3(32, 63), 256, 0, stream>>>(TT, cbuf, M0);
  // log slots: 0 special(r1+r2), 1..63 pairs(r1+r2), R3 64..95, R4 96..111,
  //            R5 112..119, R6 120..123; r7f computes 124..126 locally.
  roundk<<<dim3(32, 64), 1024, 0, stream>>>(M0, M1, sA, sB, logs, 63, 64);
  roundk<<<dim3(16, 64), 1024, 0, stream>>>(M1, M0, sB, sA, logs, 31, 96);
  roundk<<<dim3(8, 64),  1024, 0, stream>>>(M0, M1, sA, sB, logs, 15, 112);
  roundk<<<dim3(4, 64),  1024, 0, stream>>>(M1, M0, sB, sA, logs, 7, 120);
  r7f  <<<dim3(64), 1024, 0, stream>>>(M0, sA, logs, cls, out);
}

// Round 10
// 259.452 us; speedup vs baseline: 2.3515x; 1.0249x over previous
//
#include <hip/hip_runtime.h>
#include <stdint.h>

// MPS classifier forward, MI355X.
//   k1  : (127,2) blocks, 2 round-1 basis products per block (A-row split)
//   k1b : (16,63) blocks, round-2 basis TT_t = T1_p @ T2_q  (batch-independent)
//   k1c : (63,4) blocks, Gram partials over K-chunks
//   k2ns: 127 blocks: bx<63 -> coeffs/norms/logs (sums Gram partials), coeffs
//         pre-scaled by 1/n; bx>=63 -> special chain rounds 1+2
//   k2c : (32,63) combine M0 = sum_t c'_t TT_t; 2 elems/thread, 64 batches/block.
//         RULES learned: (1) every TT element read by EXACTLY ONE block (r7:
//         replication thrash); (2) launch_bounds min-waves caps VGPR=512/minw —
//         (256,8) spilled v[16][*] (r8: FETCH 1.11 GB); (3) block-uniform
//         coefficients go through SGPRs (s_load), NOT LDS — 1024 ds_read/thread
//         was ~27 us/CU of LDS traffic (r9 plateau at 48 us).
//   R3..R6: pairwise rounds (roundk, 1024 thr, 16 waves)
//   r7f : R7 + R8 + logits fused, 64 blocks

typedef unsigned short u16;
typedef __attribute__((ext_vector_type(8))) short short8;
typedef __attribute__((ext_vector_type(4))) float f32x4;

#define HP 136  // LDS row stride in bf16: 272 B, 16B-aligned, 2-way-bank-free

__device__ __forceinline__ u16 f2b(float f) {
  uint32_t u = __builtin_bit_cast(uint32_t, f);
  u += 0x7FFFu + ((u >> 16) & 1u);
  return (u16)(u >> 16);
}
__device__ __forceinline__ float b2f(u16 b) {
  uint32_t u = ((uint32_t)b) << 16;
  return __builtin_bit_cast(float, u);
}

struct AccW { f32x4 t[2][2]; };  // 16-wave config: 32x32 wave tile

// 1024-thread (16-wave) 128x128x128. A: [m][k] LDS, B: [n][k] LDS.
__device__ __forceinline__ void mfma_w16(const u16* Alds, const u16* Blds,
                                         AccW& acc) {
  const int tid = threadIdx.x;
  const int wid = tid >> 6, lane = tid & 63;
  const int wm = (wid >> 2) * 32, wn = (wid & 3) * 32;
  const int l16 = lane & 15, quad = lane >> 4;
#pragma unroll
  for (int tm = 0; tm < 2; tm++)
#pragma unroll
    for (int tn = 0; tn < 2; tn++)
      acc.t[tm][tn] = (f32x4){0.f, 0.f, 0.f, 0.f};
#pragma unroll
  for (int kk = 0; kk < 128; kk += 32) {
    short8 af[2], bf[2];
#pragma unroll
    for (int t = 0; t < 2; t++) {
      af[t] = *(const short8*)(Alds + (wm + t * 16 + l16) * HP + kk + quad * 8);
      bf[t] = *(const short8*)(Blds + (wn + t * 16 + l16) * HP + kk + quad * 8);
    }
#pragma unroll
    for (int tm = 0; tm < 2; tm++)
#pragma unroll
      for (int tn = 0; tn < 2; tn++)
        acc.t[tm][tn] = __builtin_amdgcn_mfma_f32_16x16x32_bf16(
            af[tm], bf[tn], acc.t[tm][tn], 0, 0, 0);
  }
}

__device__ __forceinline__ float acc_sumsq(const AccW& acc) {
  float ss = 0.f;
#pragma unroll
  for (int tm = 0; tm < 2; tm++)
#pragma unroll
    for (int tn = 0; tn < 2; tn++)
#pragma unroll
      for (int i = 0; i < 4; i++) {
        float v = acc.t[tm][tn][i];
        ss += v * v;
      }
  return ss;
}

// Write acc into bounce LDS (stride HP). transposed -> buffer row = col index.
// C/D layout (m89): row = quad*4 + reg, col = lane&15 per 16x16 tile.
__device__ __forceinline__ void bounce_store(u16* Lb, const AccW& acc, float scale,
                                             bool transposed) {
  const int tid = threadIdx.x;
  const int wid = tid >> 6, lane = tid & 63;
  const int wm = (wid >> 2) * 32, wn = (wid & 3) * 32;
  const int l16 = lane & 15, quad = lane >> 4;
#pragma unroll
  for (int tm = 0; tm < 2; tm++)
#pragma unroll
    for (int tn = 0; tn < 2; tn++)
#pragma unroll
      for (int i = 0; i < 4; i++) {
        int r = wm + tm * 16 + quad * 4 + i;
        int c = wn + tn * 16 + l16;
        int key = transposed ? c : r, sec = transposed ? r : c;
        Lb[key * HP + sec] = f2b(acc.t[tm][tn][i] * scale);
      }
}

// 1024 threads: copy bounce LDS -> global, fully coalesced uint4.
__device__ __forceinline__ void copy_out(const u16* Lb, u16* out) {
  const int tid = threadIdx.x;
#pragma unroll
  for (int i = 0; i < 2; i++) {
    int g8 = tid + i * 1024;  // 0..2047 uint4 units
    int row = g8 >> 4, c8 = g8 & 15;
    *(uint4*)(out + g8 * 8) = *(const uint4*)(Lb + row * HP + c8 * 8);
  }
}

__device__ __forceinline__ float block_sum(float v, float* red, int nw) {
#pragma unroll
  for (int off = 32; off > 0; off >>= 1) v += __shfl_down(v, off);
  int wid = threadIdx.x >> 6;
  if ((threadIdx.x & 63) == 0) red[wid] = v;
  __syncthreads();
  if (threadIdx.x == 0) {
    float s = 0.f;
    for (int w = 0; w < nw; w++) s += red[w];
    red[0] = s;
  }
  __syncthreads();
  float s = red[0];
  __syncthreads();
  return s;
}

// ---------------- k1: two round-1 basis products per block (A-row split) -----
__global__ __launch_bounds__(1024) void k1(const float* __restrict__ cores,
                                           u16* __restrict__ T) {
  __shared__ u16 Ald[128 * HP], B0[128 * HP], B1[128 * HP];
  const int j = blockIdx.x;   // 0..126 -> cores (2j+1, 2j+2)
  const int p = blockIdx.y;   // 0: A0 row (coeffs 1,b), 1: A1 row (coeffs a,ab)
  const float* c1 = cores + (size_t)(2 * j + 1) * 32768;
  const float* c2 = cores + (size_t)(2 * j + 2) * 32768;
  const int tid = threadIdx.x;
#pragma unroll 4
  for (int i = 0; i < 16; i++) {
    int lh = tid + i * 1024;
    int l = lh >> 7, h = lh & 127;
    float a0 = c1[(l * 2 + 0) * 128 + h];
    float av = p ? (c1[(l * 2 + 1) * 128 + h] - a0) : a0;
    Ald[l * HP + h] = f2b(av);
    float b0 = c2[(l * 2 + 0) * 128 + h];
    float b1 = c2[(l * 2 + 1) * 128 + h];
    B0[h * HP + l] = f2b(b0);  // B basis transposed in LDS
    B1[h * HP + l] = f2b(b1 - b0);
  }
  __syncthreads();
  const bool tr = (j % 2) == 0;  // even -> consumed as B operand -> store C^T
  u16* Tj = T + ((size_t)j * 4 + p * 2) * 16384;
  AccW q0, q1;
  mfma_w16(Ald, B0, q0);
  mfma_w16(Ald, B1, q1);
  __syncthreads();  // A dead -> bounce
  bounce_store(Ald, q0, 1.f, tr); __syncthreads();
  copy_out(Ald, Tj + 0 * 16384);  __syncthreads();
  bounce_store(Ald, q1, 1.f, tr); __syncthreads();
  copy_out(Ald, Tj + 1 * 16384);
}

// ---------------- k1b: round-2 basis TT_t = T1_p @ T2_q ----------------
__global__ __launch_bounds__(1024, 8) void k1b(const u16* __restrict__ T,
                                               u16* __restrict__ TT) {
  __shared__ u16 Ald[128 * HP], Bld[128 * HP];
  const int t = blockIdx.x;   // 0..15 : p = t>>2, q = t&3
  const int j2 = blockIdx.y;  // 0..62
  const int m1 = 2 * j2 + 1, m2 = 2 * j2 + 2;
  const u16* TA = T + ((size_t)m1 * 4 + (t >> 2)) * 16384;  // odd -> row-major
  const u16* TB = T + ((size_t)m2 * 4 + (t & 3)) * 16384;   // even -> [n][k] flat
  const int tid = threadIdx.x;
#pragma unroll
  for (int i = 0; i < 2; i++) {
    int g8 = tid + i * 1024;
    int r = g8 >> 4, c8 = g8 & 15;
    *(uint4*)(Ald + r * HP + c8 * 8) = *(const uint4*)(TA + g8 * 8);
    *(uint4*)(Bld + r * HP + c8 * 8) = *(const uint4*)(TB + g8 * 8);
  }
  __syncthreads();
  AccW acc;
  mfma_w16(Ald, Bld, acc);
  __syncthreads();
  bounce_store(Ald, acc, 1.f, (j2 % 2) == 0);
  __syncthreads();
  copy_out(Ald, TT + ((size_t)j2 * 16 + t) * 16384);
}

// ---------------- k1c: Gram partials G[j2][kc] = V V^T over K-chunk ----------
__global__ __launch_bounds__(256) void k1c(const u16* __restrict__ TT,
                                           float* __restrict__ Gpart) {
  __shared__ float Gp[1024];
  const int j2 = blockIdx.x, kc = blockIdx.y;
  const int tid = threadIdx.x;
  const int w = tid >> 6, lane = tid & 63;
  const int l16 = lane & 15, quad = lane >> 4;
  const u16* V = TT + (size_t)j2 * 16 * 16384 + (size_t)l16 * 16384;
  const int k0 = kc * 4096 + w * 1024;
  f32x4 acc = (f32x4){0.f, 0.f, 0.f, 0.f};
  for (int kk = k0; kk < k0 + 1024; kk += 32) {
    short8 av = *(const short8*)(V + kk + quad * 8);
    acc = __builtin_amdgcn_mfma_f32_16x16x32_bf16(av, av, acc, 0, 0, 0);
  }
#pragma unroll
  for (int i = 0; i < 4; i++)
    Gp[w * 256 + (quad * 4 + i) * 16 + l16] = acc[i];
  __syncthreads();
  Gpart[((size_t)j2 * 4 + kc) * 256 + tid] =
      Gp[tid] + Gp[256 + tid] + Gp[512 + tid] + Gp[768 + tid];
}

// ---------------- k2ns: coeffs/norms/logs (bx<63) + special chain (bx>=63) ----
__global__ __launch_bounds__(128) void k2ns(const float* __restrict__ x,
                                            const float* __restrict__ Gpart,
                                            const float* __restrict__ core0,
                                            const float* __restrict__ cores,
                                            const u16* __restrict__ T,
                                            float* __restrict__ cbuf,
                                            float* __restrict__ sA,
                                            float* __restrict__ logs) {
  __shared__ float Gs[256];
  __shared__ float svec[128];
  __shared__ float red[8];
  const int bx = blockIdx.x, tid = threadIdx.x;
  if (bx < 63) {
    const int j2 = bx;
#pragma unroll
    for (int i = 0; i < 2; i++) {
      int t2 = tid + i * 128;
      float s = 0.f;
#pragma unroll
      for (int kc = 0; kc < 4; kc++)
        s += Gpart[((size_t)j2 * 4 + kc) * 256 + t2];
      Gs[t2] = s;
    }
    __syncthreads();
    if (tid < 64) {
      const int b = tid;
      const float* xb = x + b * 256;
      const int m1 = 2 * j2 + 1, m2 = 2 * j2 + 2;
      float a1 = xb[2 * m1 + 2], b1 = xb[2 * m1 + 3];
      float a2 = xb[2 * m2 + 2], b2 = xb[2 * m2 + 3];
      float c1[4] = {1.f, b1, a1, a1 * b1};
      float c2[4] = {1.f, b2, a2, a2 * b2};
      float c[16];
#pragma unroll
      for (int p = 0; p < 4; p++)
#pragma unroll
        for (int q = 0; q < 4; q++) c[p * 4 + q] = c1[p] * c2[q];
      float n2 = 0.f;
#pragma unroll
      for (int t = 0; t < 16; t++) {
        float s = 0.f;
#pragma unroll
        for (int u = 0; u < 16; u++) s += Gs[t * 16 + u] * c[u];
        n2 += c[t] * s;
      }
      float n = fmaxf(sqrtf(n2), 1e-12f);
      logs[b * 127 + 1 + j2] = logf(n);
      float inv = 1.f / n;
#pragma unroll
      for (int t = 0; t < 16; t++)
        cbuf[((size_t)j2 * 64 + b) * 16 + t] = c[t] * inv;  // prescaled by 1/n
    }
  } else {
    const int b = bx - 63;
    const float* xb = x + b * 256;
    float x0 = xb[0], x1 = xb[1];
    svec[tid] = core0[tid] * (1.f - x0) + core0[128 + tid] * x0;
    __syncthreads();
    float acc1 = 0.f;
    for (int k = 0; k < 128; k++) {
      float m0 = cores[(k * 2 + 0) * 128 + tid];
      float m1 = cores[(k * 2 + 1) * 128 + tid];
      acc1 += svec[k] * (m0 + x1 * (m1 - m0));
    }
    float tot = block_sum(acc1 * acc1, red, 2);
    float n1 = fmaxf(sqrtf(tot), 1e-12f);
    float ln = logf(n1);
    svec[tid] = acc1 / n1;
    __syncthreads();
    float a = xb[2], bb = xb[3], ab = a * bb;
    float acc2 = 0.f;
    for (int k8 = 0; k8 < 16; k8++) {
      union { uint4 v; u16 s[8]; } q00, q01, q10, q11;
      q00.v = *(const uint4*)(T + tid * 128 + k8 * 8);
      q01.v = *(const uint4*)(T + 16384 + tid * 128 + k8 * 8);
      q10.v = *(const uint4*)(T + 32768 + tid * 128 + k8 * 8);
      q11.v = *(const uint4*)(T + 49152 + tid * 128 + k8 * 8);
#pragma unroll
      for (int e = 0; e < 8; e++) {
        float pk = b2f(q00.s[e]) + a * b2f(q10.s[e]) + bb * b2f(q01.s[e]) +
                   ab * b2f(q11.s[e]);
        acc2 += svec[k8 * 8 + e] * pk;
      }
    }
    float tot2 = block_sum(acc2 * acc2, red, 2);
    float n2 = fmaxf(sqrtf(tot2), 1e-12f);
    sA[b * 128 + tid] = acc2 / n2;
    if (tid == 0) logs[b * 127 + 0] = ln + logf(n2);
  }
}

// ---------------- k2c: combine; coefficients via scalar (SGPR) loads ---------
// grid (32,63): each TT element read by exactly one block (no replication).
// (256,4): 128-VGPR cap, v[16][2] fits. Coefficients are block-uniform ->
// uniform-address float4 loads lower to s_load_dwordx4 (no LDS, no VALU).
__global__ __launch_bounds__(256, 4) void k2c(const u16* __restrict__ TT,
                                              const float* __restrict__ cbuf,
                                              u16* __restrict__ M0) {
  const int slice = blockIdx.x;  // 0..31, 512 elems each
  const int j2 = blockIdx.y;
  const int tid = threadIdx.x;
  const int e0 = slice * 512 + tid * 2;
  float v[16][2];
#pragma unroll
  for (int t = 0; t < 16; t++) {
    union { uint32_t u; u16 s[2]; } q;
    q.u = *(const uint32_t*)(TT + ((size_t)j2 * 16 + t) * 16384 + e0);
    v[t][0] = b2f(q.s[0]);
    v[t][1] = b2f(q.s[1]);
  }
  const float4* cb4 = (const float4*)(cbuf + (size_t)j2 * 1024);  // uniform base
  u16* out = M0 + (size_t)j2 * 16384 + e0;
#pragma unroll 4
  for (int b = 0; b < 64; b++) {
    float4 c0 = cb4[b * 4 + 0];
    float4 c1 = cb4[b * 4 + 1];
    float4 c2 = cb4[b * 4 + 2];
    float4 c3 = cb4[b * 4 + 3];
    float cc[16] = {c0.x, c0.y, c0.z, c0.w, c1.x, c1.y, c1.z, c1.w,
                    c2.x, c2.y, c2.z, c2.w, c3.x, c3.y, c3.z, c3.w};
    float o0 = 0.f, o1 = 0.f;
#pragma unroll
    for (int t = 0; t < 16; t++) {
      o0 += cc[t] * v[t][0];
      o1 += cc[t] * v[t][1];
    }
    union { uint32_t u; u16 s[2]; } r;
    r.s[0] = f2b(o0);
    r.s[1] = f2b(o1);
    *(uint32_t*)(out + (size_t)b * 63 * 16384) = r.u;
  }
}

// ---------------- R3..R6: pairwise round (1024 threads) ----------------
__global__ __launch_bounds__(1024, 8) void roundk(const u16* __restrict__ In,
                                                  u16* __restrict__ Out,
                                                  const float* __restrict__ sIn,
                                                  float* __restrict__ sOut,
                                                  float* __restrict__ logs,
                                                  int count_in, int slot0) {
  __shared__ u16 Ald[128 * HP], Bld[128 * HP];
  __shared__ float red[16];
  const int b = blockIdx.y, p = blockIdx.x, tid = threadIdx.x;

  if (p == 0) {
    float* svec = (float*)Ald;
    if (tid < 128) svec[tid] = sIn[b * 128 + tid];
    __syncthreads();
    const u16* M = In + (size_t)b * count_in * 16384;  // In[b][0], transposed
    float acc = 0.f;
    if (tid < 128) {
      for (int k8 = 0; k8 < 16; k8++) {
        union { uint4 v; u16 s[8]; } q;
        q.v = *(const uint4*)(M + tid * 128 + k8 * 8);
#pragma unroll
        for (int e = 0; e < 8; e++) acc += svec[k8 * 8 + e] * b2f(q.s[e]);
      }
    }
    float tot = block_sum((tid < 128) ? acc * acc : 0.f, red, 16);
    float n = fmaxf(sqrtf(tot), 1e-12f);
    if (tid < 128) sOut[b * 128 + tid] = acc / n;
    if (tid == 0) logs[b * 127 + slot0] = logf(n);
  } else {
    const u16* A = In + ((size_t)b * count_in + (2 * p - 1)) * 16384;
    const u16* Bm = In + ((size_t)b * count_in + (2 * p)) * 16384;
#pragma unroll
    for (int i = 0; i < 2; i++) {
      int g8 = tid + i * 1024;
      int r = g8 >> 4, c8 = g8 & 15;
      *(uint4*)(Ald + r * HP + c8 * 8) = *(const uint4*)(A + g8 * 8);
      *(uint4*)(Bld + r * HP + c8 * 8) = *(const uint4*)(Bm + g8 * 8);
    }
    __syncthreads();
    AccW acc;
    mfma_w16(Ald, Bld, acc);
    float tot = block_sum(acc_sumsq(acc), red, 16);
    float n = fmaxf(sqrtf(tot), 1e-12f);
    if (tid == 0) logs[b * 127 + slot0 + p] = logf(n);
    int m = p - 1;
    int count_out = (count_in - 1) / 2;
    bounce_store(Ald, acc, 1.f / n, (m % 2) == 0);  // block_sum ended w/ barrier
    __syncthreads();
    copy_out(Ald, Out + ((size_t)b * count_out + m) * 16384);
  }
}

// ---------------- r7f: R7 + R8 + logits, one block per batch ----------------
__global__ __launch_bounds__(1024, 8) void r7f(const u16* __restrict__ In,
                                               const float* __restrict__ sIn,
                                               const float* __restrict__ logs,
                                               const float* __restrict__ cls,
                                               float* __restrict__ out) {
  __shared__ u16 Ald[128 * HP], Bld[128 * HP];
  __shared__ float svec[128], ovec[128], red[16];
  const int b = blockIdx.x, tid = threadIdx.x;
  if (tid < 128) svec[tid] = sIn[b * 128 + tid];
  const u16* A = In + ((size_t)b * 3 + 1) * 16384;   // row-major
  const u16* Bm = In + ((size_t)b * 3 + 2) * 16384;  // transposed
#pragma unroll
  for (int i = 0; i < 2; i++) {
    int g8 = tid + i * 1024;
    int r = g8 >> 4, c8 = g8 & 15;
    *(uint4*)(Ald + r * HP + c8 * 8) = *(const uint4*)(A + g8 * 8);
    *(uint4*)(Bld + r * HP + c8 * 8) = *(const uint4*)(Bm + g8 * 8);
  }
  __syncthreads();
  AccW acc;
  mfma_w16(Ald, Bld, acc);
  float tot = block_sum(acc_sumsq(acc), red, 16);
  float n1 = fmaxf(sqrtf(tot), 1e-12f);
  float lg = logf(n1);
  // C (normalized) -> bounce LDS transposed: Lb[c*HP + r]
  bounce_store(Ald, acc, 1.f / n1, true);
  // special dot with In[b*3+0] (global, transposed layout)
  const u16* M0p = In + (size_t)b * 3 * 16384;
  float acc0 = 0.f;
  if (tid < 128) {
    for (int k8 = 0; k8 < 16; k8++) {
      union { uint4 v; u16 s[8]; } q;
      q.v = *(const uint4*)(M0p + tid * 128 + k8 * 8);
#pragma unroll
      for (int e = 0; e < 8; e++) acc0 += svec[k8 * 8 + e] * b2f(q.s[e]);
    }
  }
  float tot0 = block_sum((tid < 128) ? acc0 * acc0 : 0.f, red, 16);
  float n0 = fmaxf(sqrtf(tot0), 1e-12f);
  lg += logf(n0);
  if (tid < 128) ovec[tid] = acc0 / n0;
  __syncthreads();
  // R8: res[c] = sum_r ovec[r] * C[r][c]  (C in Ald as [c][r])
  float acc2 = 0.f;
  if (tid < 128) {
    for (int r = 0; r < 128; r++) acc2 += ovec[r] * b2f(Ald[tid * HP + r]);
  }
  float tot2 = block_sum((tid < 128) ? acc2 * acc2 : 0.f, red, 16);
  float n2 = fmaxf(sqrtf(tot2), 1e-12f);
  lg += logf(n2);
  if (tid < 128) svec[tid] = acc2 / n2;
  __syncthreads();
  if (tid < 10) {
    float a = 0.f;
    for (int h = 0; h < 128; h++) a += svec[h] * cls[tid * 128 + h];
    float L = lg;
    for (int i = 0; i < 124; i++) L += logs[b * 127 + i];
    out[b * 10 + tid] = a + L;
  }
}

extern "C" void kernel_launch(void* const* d_in, const int* in_sizes, int n_in,
                              void* d_out, int out_size, void* d_ws, size_t ws_size,
                              hipStream_t stream) {
  (void)in_sizes; (void)n_in; (void)out_size; (void)ws_size;
  const float* x     = (const float*)d_in[0];  // (64,256)
  const float* core0 = (const float*)d_in[1];  // (1,2,128)
  const float* cores = (const float*)d_in[2];  // (255,128,2,128)
  const float* cls   = (const float*)d_in[3];  // (10,128)
  float* out = (float*)d_out;
  char* ws = (char*)d_ws;

  // Region A (65 MB): early = T (16.6 MB) + TT (33 MB); later reused as M1.
  constexpr size_t SZ_T  = (size_t)127 * 4 * 16384 * 2;   //  16,646,144
  constexpr size_t SZ_A  = (size_t)64 * 31 * 16384 * 2;   //  65,011,712 (M1)
  constexpr size_t SZ_M0 = (size_t)64 * 63 * 16384 * 2;   // 132,120,576

  u16*   T    = (u16*)(ws);
  u16*   TT   = (u16*)(ws + SZ_T);
  u16*   M1   = (u16*)(ws);            // aliases T+TT after k2c completes
  u16*   M0   = (u16*)(ws + SZ_A);
  char*  tail0 = ws + SZ_A + SZ_M0;
  float* Gpart = (float*)(tail0);                      // 63*4*256*4 = 258,048
  float* cbuf = (float*)(tail0 + 262144);              // 63*64*16*4 = 258,048
  float* sA   = (float*)(tail0 + 262144 + 262144);
  float* sB   = (float*)(tail0 + 262144 + 262144 + 32768);
  float* logs = (float*)(tail0 + 262144 + 262144 + 65536);

  k1  <<<dim3(127, 2), 1024, 0, stream>>>(cores, T);
  k1b <<<dim3(16, 63), 1024, 0, stream>>>(T, TT);
  k1c <<<dim3(63, 4), 256, 0, stream>>>(TT, Gpart);
  k2ns<<<dim3(127), 128, 0, stream>>>(x, Gpart, core0, cores, T, cbuf, sA, logs);
  k2c <<<dim3(32, 63), 256, 0, stream>>>(TT, cbuf, M0);
  // log slots: 0 special(r1+r2), 1..63 pairs(r1+r2), R3 64..95, R4 96..111,
  //            R5 112..119, R6 120..123; r7f computes 124..126 locally.
  roundk<<<dim3(32, 64), 1024, 0, stream>>>(M0, M1, sA, sB, logs, 63, 64);
  roundk<<<dim3(16, 64), 1024, 0, stream>>>(M1, M0, sB, sA, logs, 31, 96);
  roundk<<<dim3(8, 64),  1024, 0, stream>>>(M0, M1, sA, sB, logs, 15, 112);
  roundk<<<dim3(4, 64),  1024, 0, stream>>>(M1, M0, sB, sA, logs, 7, 120);
  r7f  <<<dim3(64), 1024, 0, stream>>>(M0, sA, logs, cls, out);
}